// Round 1
// baseline (4451.949 us; speedup 1.0000x reference)
//
#include <hip/hip_runtime.h>
#include <cstdint>
#include <cstddef>

// Problem constants (B,S,D,H fixed by the reference)
#define B_  256
#define S_  128
#define D_  1024
#define H_  8
#define DH_ 128
#define M_  (B_ * S_)   // 32768 rows

// GEMM tiling
#define BM 128
#define BN 128
#define BK 16

// ---------------------------------------------------------------------------
// K1: QKV projection.  out[h, m, f] = relu(sum_d code[m,d] * W[h,d,f] + b[h,f])
// Grid: (M/BM = 256, 24) ; blockIdx.y -> (qkv = y>>3, h = y&7), N-tile == DH.
// ---------------------------------------------------------------------------
__global__ __launch_bounds__(256, 2)
void gemm_proj(const float* __restrict__ code,
               const float* __restrict__ Wq, const float* __restrict__ bq,
               const float* __restrict__ Wk, const float* __restrict__ bk,
               const float* __restrict__ Wv, const float* __restrict__ bv,
               float* __restrict__ Qbuf, float* __restrict__ Kbuf, float* __restrict__ Vbuf)
{
    __shared__ float As[BK][BM + 4];   // A stored transposed: As[k][m]
    __shared__ float Bs[BK][BN + 4];   // B natural: Bs[k][n]

    const int tid = threadIdx.x;
    const int tx = tid & 15, ty = tid >> 4;
    const int m0 = blockIdx.x * BM;
    const int nt = blockIdx.y;
    const int qkv = nt >> 3, h = nt & 7;

    const float* W    = (qkv == 0 ? Wq : (qkv == 1 ? Wk : Wv)) + (size_t)h * D_ * DH_;
    const float* bias = (qkv == 0 ? bq : (qkv == 1 ? bk : bv)) + h * DH_;
    float* out        = (qkv == 0 ? Qbuf : (qkv == 1 ? Kbuf : Vbuf)) + (size_t)h * M_ * DH_;

    float acc[8][8] = {};

    for (int k0 = 0; k0 < D_; k0 += BK) {
        // A tile: 128 rows x 16 cols, transposed store (2-way bank alias only)
        #pragma unroll
        for (int l = 0; l < 2; ++l) {
            int idx = tid + l * 256;
            int row = idx >> 2, c = (idx & 3) * 4;
            float4 v = *reinterpret_cast<const float4*>(&code[(size_t)(m0 + row) * D_ + k0 + c]);
            As[c + 0][row] = v.x; As[c + 1][row] = v.y;
            As[c + 2][row] = v.z; As[c + 3][row] = v.w;
        }
        // B tile: 16 rows x 128 cols, natural store
        #pragma unroll
        for (int l = 0; l < 2; ++l) {
            int idx = tid + l * 256;
            int row = idx >> 5, c = (idx & 31) * 4;
            *reinterpret_cast<float4*>(&Bs[row][c]) =
                *reinterpret_cast<const float4*>(&W[(size_t)(k0 + row) * DH_ + c]);
        }
        __syncthreads();
        #pragma unroll
        for (int kk = 0; kk < BK; ++kk) {
            float a[8], b[8];
            *reinterpret_cast<float4*>(&a[0]) = *reinterpret_cast<const float4*>(&As[kk][ty * 8]);
            *reinterpret_cast<float4*>(&a[4]) = *reinterpret_cast<const float4*>(&As[kk][ty * 8 + 4]);
            *reinterpret_cast<float4*>(&b[0]) = *reinterpret_cast<const float4*>(&Bs[kk][tx * 8]);
            *reinterpret_cast<float4*>(&b[4]) = *reinterpret_cast<const float4*>(&Bs[kk][tx * 8 + 4]);
            #pragma unroll
            for (int i = 0; i < 8; ++i)
                #pragma unroll
                for (int j = 0; j < 8; ++j)
                    acc[i][j] = fmaf(a[i], b[j], acc[i][j]);
        }
        __syncthreads();
    }

    #pragma unroll
    for (int i = 0; i < 8; ++i) {
        const int m = m0 + ty * 8 + i;
        float o[8];
        #pragma unroll
        for (int j = 0; j < 8; ++j) {
            float v = acc[i][j] + bias[tx * 8 + j];
            o[j] = v > 0.0f ? v : 0.0f;
        }
        *reinterpret_cast<float4*>(&out[(size_t)m * DH_ + tx * 8])     = *reinterpret_cast<float4*>(&o[0]);
        *reinterpret_cast<float4*>(&out[(size_t)m * DH_ + tx * 8 + 4]) = *reinterpret_cast<float4*>(&o[4]);
    }
}

// ---------------------------------------------------------------------------
// K2: per-(h,b) attention + PDG normalization + PV.
// Grid: (B_, H_); 256 threads. All of pdg (128x128) lives in LDS.
// rel(h<4):  R[b,s,t] + h*(s==t)      rel(h>=4): R[b,t,s]
// ---------------------------------------------------------------------------
__global__ __launch_bounds__(256, 2)
void attn_pdg(const float* __restrict__ Qbuf, const float* __restrict__ Kbuf,
              const float* __restrict__ Vbuf, const float* __restrict__ Rel,
              float* __restrict__ resbuf)
{
    __shared__ float pdg[S_][S_ + 1];       // 66 KB
    __shared__ float stA[BK][S_ + 4];       // Q^T staging
    __shared__ float stB[BK][S_ + 4];       // K^T / V staging
    __shared__ unsigned rbits[S_][4];       // relation bitmask: bit t of row s
    __shared__ float inv_in[S_], inv_out[S_];

    const int tid = threadIdx.x;
    const int tx = tid & 15, ty = tid >> 4;
    const int b = blockIdx.x, h = blockIdx.y;
    const int wid = tid >> 6, lane = tid & 63;

    // Phase 0: pack R[b] (exact 0/1 floats) into a bitmask via ballot
    for (int s = wid; s < S_; s += 4) {
        const float* row = &Rel[((size_t)b * S_ + s) * S_];
        unsigned long long b0 = __ballot(row[lane] > 0.5f);
        unsigned long long b1 = __ballot(row[64 + lane] > 0.5f);
        if (lane == 0) {
            rbits[s][0] = (unsigned)b0; rbits[s][1] = (unsigned)(b0 >> 32);
            rbits[s][2] = (unsigned)b1; rbits[s][3] = (unsigned)(b1 >> 32);
        }
    }

    const size_t base = ((size_t)h * M_ + (size_t)b * S_) * DH_;
    const float* Q = Qbuf + base;
    const float* K = Kbuf + base;
    const float* V = Vbuf + base;

    // Phase 1: attn = Q K^T  -> acc[i][j], s = ty*8+i, t = tx*8+j
    float acc[8][8] = {};
    for (int k0 = 0; k0 < DH_; k0 += BK) {
        #pragma unroll
        for (int l = 0; l < 2; ++l) {
            int idx = tid + l * 256;
            int row = idx >> 2, c = (idx & 3) * 4;
            float4 vq = *reinterpret_cast<const float4*>(&Q[(size_t)row * DH_ + k0 + c]);
            stA[c + 0][row] = vq.x; stA[c + 1][row] = vq.y;
            stA[c + 2][row] = vq.z; stA[c + 3][row] = vq.w;
            float4 vk = *reinterpret_cast<const float4*>(&K[(size_t)row * DH_ + k0 + c]);
            stB[c + 0][row] = vk.x; stB[c + 1][row] = vk.y;
            stB[c + 2][row] = vk.z; stB[c + 3][row] = vk.w;
        }
        __syncthreads();
        #pragma unroll
        for (int kk = 0; kk < BK; ++kk) {
            float a[8], bb[8];
            *reinterpret_cast<float4*>(&a[0])  = *reinterpret_cast<const float4*>(&stA[kk][ty * 8]);
            *reinterpret_cast<float4*>(&a[4])  = *reinterpret_cast<const float4*>(&stA[kk][ty * 8 + 4]);
            *reinterpret_cast<float4*>(&bb[0]) = *reinterpret_cast<const float4*>(&stB[kk][tx * 8]);
            *reinterpret_cast<float4*>(&bb[4]) = *reinterpret_cast<const float4*>(&stB[kk][tx * 8 + 4]);
            #pragma unroll
            for (int i = 0; i < 8; ++i)
                #pragma unroll
                for (int j = 0; j < 8; ++j)
                    acc[i][j] = fmaf(a[i], bb[j], acc[i][j]);
        }
        __syncthreads();
    }

    // Phase 2: pdg = rel*attn + 1e-11 into LDS
    #pragma unroll
    for (int i = 0; i < 8; ++i) {
        int s = ty * 8 + i;
        #pragma unroll
        for (int j = 0; j < 8; ++j) {
            int t = tx * 8 + j;
            float r;
            if (h < H_ / 2) {
                r = (float)((rbits[s][t >> 5] >> (t & 31)) & 1u);
                if (s == t) r += (float)h;
            } else {
                r = (float)((rbits[t][s >> 5] >> (s & 31)) & 1u);
            }
            pdg[s][t] = r * acc[i][j] + 1e-11f;
        }
    }
    __syncthreads();

    // Phase 3: degree sums.  indeg over rows s (axis=2) -> per column t;
    // outdeg over cols t (axis=3) -> per row s.
    if (tid < S_) {
        const int t = tid;
        float sum = 0.0f;
        for (int s = 0; s < S_; ++s) sum += pdg[s][t];
        inv_in[t] = 1.0f / sqrtf(sum);
    } else {
        const int s = tid - S_;
        float sum = 0.0f;
        for (int t = 0; t < S_; ++t) sum += pdg[s][t];
        inv_out[s] = 1.0f / sqrtf(sum);
    }
    __syncthreads();

    // Phase 4: softed = rel * (rel*attn + eps) * inv_in[t] * inv_out[s], in place
    #pragma unroll
    for (int i = 0; i < 8; ++i) {
        int s = ty * 8 + i;
        #pragma unroll
        for (int j = 0; j < 8; ++j) {
            int t = tx * 8 + j;
            float r;
            if (h < H_ / 2) {
                r = (float)((rbits[s][t >> 5] >> (t & 31)) & 1u);
                if (s == t) r += (float)h;
            } else {
                r = (float)((rbits[t][s >> 5] >> (s & 31)) & 1u);
            }
            float p = r * acc[i][j] + 1e-11f;
            pdg[s][t] = r * p * inv_in[t] * inv_out[s];
        }
    }
    __syncthreads();

    // Phase 5: res = softed @ V  (softed from LDS, V staged in 16-row chunks)
    float acc2[8][8] = {};
    for (int t0 = 0; t0 < S_; t0 += BK) {
        #pragma unroll
        for (int l = 0; l < 2; ++l) {
            int idx = tid + l * 256;
            int row = idx >> 5, c = (idx & 31) * 4;
            *reinterpret_cast<float4*>(&stB[row][c]) =
                *reinterpret_cast<const float4*>(&V[(size_t)(t0 + row) * DH_ + c]);
        }
        __syncthreads();
        #pragma unroll
        for (int kk = 0; kk < BK; ++kk) {
            float a[8], bb[8];
            #pragma unroll
            for (int i = 0; i < 8; ++i) a[i] = pdg[ty * 8 + i][t0 + kk];  // broadcast reads
            *reinterpret_cast<float4*>(&bb[0]) = *reinterpret_cast<const float4*>(&stB[kk][tx * 8]);
            *reinterpret_cast<float4*>(&bb[4]) = *reinterpret_cast<const float4*>(&stB[kk][tx * 8 + 4]);
            #pragma unroll
            for (int i = 0; i < 8; ++i)
                #pragma unroll
                for (int j = 0; j < 8; ++j)
                    acc2[i][j] = fmaf(a[i], bb[j], acc2[i][j]);
        }
        __syncthreads();
    }

    // Phase 6: write res into concat layout resbuf[b*S+s][h*DH + f]
    #pragma unroll
    for (int i = 0; i < 8; ++i) {
        int s = ty * 8 + i;
        size_t o = ((size_t)b * S_ + s) * D_ + h * DH_ + tx * 8;
        float4 v0 = make_float4(acc2[i][0], acc2[i][1], acc2[i][2], acc2[i][3]);
        float4 v1 = make_float4(acc2[i][4], acc2[i][5], acc2[i][6], acc2[i][7]);
        *reinterpret_cast<float4*>(&resbuf[o])     = v0;
        *reinterpret_cast<float4*>(&resbuf[o + 4]) = v1;
    }
}

// ---------------------------------------------------------------------------
// K3: output projection. out = relu([resbuf | code] @ Wo + bo)
// A is the virtual concat [M, 2048]; K-chunks never straddle the 1024 seam.
// Grid: (256, 8)
// ---------------------------------------------------------------------------
__global__ __launch_bounds__(256, 2)
void gemm_out(const float* __restrict__ resbuf, const float* __restrict__ code,
              const float* __restrict__ Wo, const float* __restrict__ bo,
              float* __restrict__ out)
{
    __shared__ float As[BK][BM + 4];
    __shared__ float Bs[BK][BN + 4];

    const int tid = threadIdx.x;
    const int tx = tid & 15, ty = tid >> 4;
    const int m0 = blockIdx.x * BM;
    const int n0 = blockIdx.y * BN;

    float acc[8][8] = {};

    for (int k0 = 0; k0 < 2 * D_; k0 += BK) {
        const float* Asrc = (k0 < D_) ? (resbuf + k0) : (code + (k0 - D_));
        #pragma unroll
        for (int l = 0; l < 2; ++l) {
            int idx = tid + l * 256;
            int row = idx >> 2, c = (idx & 3) * 4;
            float4 v = *reinterpret_cast<const float4*>(&Asrc[(size_t)(m0 + row) * D_ + c]);
            As[c + 0][row] = v.x; As[c + 1][row] = v.y;
            As[c + 2][row] = v.z; As[c + 3][row] = v.w;
        }
        #pragma unroll
        for (int l = 0; l < 2; ++l) {
            int idx = tid + l * 256;
            int row = idx >> 5, c = (idx & 31) * 4;
            *reinterpret_cast<float4*>(&Bs[row][c]) =
                *reinterpret_cast<const float4*>(&Wo[(size_t)(k0 + row) * D_ + n0 + c]);
        }
        __syncthreads();
        #pragma unroll
        for (int kk = 0; kk < BK; ++kk) {
            float a[8], b[8];
            *reinterpret_cast<float4*>(&a[0]) = *reinterpret_cast<const float4*>(&As[kk][ty * 8]);
            *reinterpret_cast<float4*>(&a[4]) = *reinterpret_cast<const float4*>(&As[kk][ty * 8 + 4]);
            *reinterpret_cast<float4*>(&b[0]) = *reinterpret_cast<const float4*>(&Bs[kk][tx * 8]);
            *reinterpret_cast<float4*>(&b[4]) = *reinterpret_cast<const float4*>(&Bs[kk][tx * 8 + 4]);
            #pragma unroll
            for (int i = 0; i < 8; ++i)
                #pragma unroll
                for (int j = 0; j < 8; ++j)
                    acc[i][j] = fmaf(a[i], b[j], acc[i][j]);
        }
        __syncthreads();
    }

    #pragma unroll
    for (int i = 0; i < 8; ++i) {
        const int m = m0 + ty * 8 + i;
        float o[8];
        #pragma unroll
        for (int j = 0; j < 8; ++j) {
            float v = acc[i][j] + bo[n0 + tx * 8 + j];
            o[j] = v > 0.0f ? v : 0.0f;
        }
        *reinterpret_cast<float4*>(&out[(size_t)m * D_ + n0 + tx * 8])     = *reinterpret_cast<float4*>(&o[0]);
        *reinterpret_cast<float4*>(&out[(size_t)m * D_ + n0 + tx * 8 + 4]) = *reinterpret_cast<float4*>(&o[4]);
    }
}

// ---------------------------------------------------------------------------
extern "C" void kernel_launch(void* const* d_in, const int* in_sizes, int n_in,
                              void* d_out, int out_size, void* d_ws, size_t ws_size,
                              hipStream_t stream)
{
    const float* code = (const float*)d_in[0];
    const float* Rel  = (const float*)d_in[1];
    const float* Wq   = (const float*)d_in[2];
    const float* bq   = (const float*)d_in[3];
    const float* Wk   = (const float*)d_in[4];
    const float* bk   = (const float*)d_in[5];
    const float* Wv   = (const float*)d_in[6];
    const float* bv   = (const float*)d_in[7];
    const float* Wo   = (const float*)d_in[8];
    const float* bo   = (const float*)d_in[9];
    float* out = (float*)d_out;

    // Workspace layout: Q, K, V ([H][M][DH]) then res ([M][D]).
    // Requires 4 * 134,217,728 B = 512 MiB of ws.
    const size_t nQKV = (size_t)H_ * M_ * DH_;   // 33,554,432 floats each
    float* Qbuf   = (float*)d_ws;
    float* Kbuf   = Qbuf + nQKV;
    float* Vbuf   = Kbuf + nQKV;
    float* resbuf = Vbuf + nQKV;
    (void)in_sizes; (void)n_in; (void)out_size; (void)ws_size;

    gemm_proj<<<dim3(M_ / BM, 24), 256, 0, stream>>>(code, Wq, bq, Wk, bk, Wv, bv,
                                                     Qbuf, Kbuf, Vbuf);
    attn_pdg<<<dim3(B_, H_), 256, 0, stream>>>(Qbuf, Kbuf, Vbuf, Rel, resbuf);
    gemm_out<<<dim3(M_ / BM, D_ / BN), 256, 0, stream>>>(resbuf, code, Wo, bo, out);
}

// Round 3
// 975.041 us; speedup vs baseline: 4.5659x; 4.5659x over previous
//
#include <hip/hip_runtime.h>
#include <cstdint>
#include <cstddef>

// Problem constants
#define B_  256
#define S_  128
#define D_  1024
#define H_  8
#define DH_ 128
#define M_  (B_ * S_)   // 32768 rows

typedef _Float16 half8 __attribute__((ext_vector_type(8)));
typedef float    f32x4 __attribute__((ext_vector_type(4)));

#define GLOAD_LDS16(gp, lp)                                                    \
    __builtin_amdgcn_global_load_lds(                                          \
        (const __attribute__((address_space(1))) void*)(gp),                   \
        (__attribute__((address_space(3))) void*)(lp), 16, 0, 0)

// ---------------------------------------------------------------------------
// Conversion kernels (run once at the head of the graph)
// ---------------------------------------------------------------------------
__global__ __launch_bounds__(256)
void cvt_code(const float* __restrict__ src, _Float16* __restrict__ dst, int n8)
{
    int i = blockIdx.x * 256 + threadIdx.x;
    if (i >= n8) return;
    const float4* s = (const float4*)src;
    float4 a = s[2 * i], b = s[2 * i + 1];
    half8 o;
    o[0] = (_Float16)a.x; o[1] = (_Float16)a.y; o[2] = (_Float16)a.z; o[3] = (_Float16)a.w;
    o[4] = (_Float16)b.x; o[5] = (_Float16)b.y; o[6] = (_Float16)b.z; o[7] = (_Float16)b.w;
    *(half8*)(dst + (size_t)i * 8) = o;
}

// Wq/Wk/Wv [H][D][DH] f32 -> Wt[n][k] f16 (n = qkv*1024 + h*128 + f, k = d)
// bias_all[n] f32 from bq/bk/bv.
__global__ __launch_bounds__(256)
void cvt_wqkv(const float* __restrict__ Wq, const float* __restrict__ Wk,
              const float* __restrict__ Wv,
              const float* __restrict__ bq, const float* __restrict__ bk,
              const float* __restrict__ bv,
              _Float16* __restrict__ Wt, float* __restrict__ bias_all)
{
    int idx = blockIdx.x * 256 + threadIdx.x;   // 3072*128
    if (idx >= 3072 * 128) return;
    int n = idx >> 7, kc = idx & 127, k = kc * 8;
    int qkv = n >> 10, hf = n & 1023, h = hf >> 7, f = hf & 127;
    const float* W = (qkv == 0 ? Wq : (qkv == 1 ? Wk : Wv))
                     + (size_t)h * D_ * DH_ + (size_t)k * DH_ + f;
    half8 o;
    #pragma unroll
    for (int j = 0; j < 8; ++j) o[j] = (_Float16)W[(size_t)j * DH_];
    *(half8*)(Wt + (size_t)n * 1024 + k) = o;
    if (kc == 0)
        bias_all[n] = (qkv == 0 ? bq : (qkv == 1 ? bk : bv))[h * DH_ + f];
}

// Wo [2048 k][1024 n] f32 -> Wot [1024 n][2048 k] f16
__global__ __launch_bounds__(256)
void cvt_wo(const float* __restrict__ Wo, _Float16* __restrict__ Wot)
{
    int idx = blockIdx.x * 256 + threadIdx.x;   // 1024*256
    if (idx >= 1024 * 256) return;
    int n = idx >> 8, kc = idx & 255, k = kc * 8;
    const float* W = Wo + (size_t)k * 1024 + n;
    half8 o;
    #pragma unroll
    for (int j = 0; j < 8; ++j) o[j] = (_Float16)W[(size_t)j * 1024];
    *(half8*)(Wot + (size_t)n * 2048 + k) = o;
}

// ---------------------------------------------------------------------------
// f16 MFMA GEMM, m97 structure: 128x128 tile, BK=32, 4 waves (2x2), 4x4 frags.
// A is the virtual concat [A1 | A2] along K at seam K1 (lda = 1024 for both).
// Bt is B^T: [Ntot][Ktot] f16.  out = relu(A @ B + bias), f16 or f32 store.
// ---------------------------------------------------------------------------
template <bool OUTF32>
__global__ __launch_bounds__(256, 2)
void gemm_f16(const _Float16* __restrict__ A1, const _Float16* __restrict__ A2,
              int K1, const _Float16* __restrict__ Bt,
              const float* __restrict__ bias, void* __restrict__ outp,
              int Ntot, int Ktot)
{
    __shared__ _Float16 Ab[2][128 * 32];
    __shared__ _Float16 Bb[2][128 * 32];

    const int tid = threadIdx.x;
    const int w = tid >> 6, l = tid & 63;
    const int wr = w >> 1, wc = w & 1;
    const int m0 = blockIdx.x * 128, n0 = blockIdx.y * 128;
    const int NT = Ktot / 32;

    // staging lambda: tile t -> buffer buf
    auto stage = [&](int buf, int t) {
        const int k0 = t * 32;
        const _Float16* Asrc; int kc;
        if (k0 < K1) { Asrc = A1; kc = k0; } else { Asrc = A2; kc = k0 - K1; }
        const int r = w * 32 + (l >> 2);
        const int c = (l & 3) * 8;
        #pragma unroll
        for (int i = 0; i < 2; ++i) {
            const _Float16* g = Asrc + (size_t)(m0 + r + i * 16) * 1024 + kc + c;
            GLOAD_LDS16(g, &Ab[buf][(w * 32 + i * 16) * 32]);
        }
        #pragma unroll
        for (int i = 0; i < 2; ++i) {
            const _Float16* g = Bt + (size_t)(n0 + r + i * 16) * Ktot + k0 + c;
            GLOAD_LDS16(g, &Bb[buf][(w * 32 + i * 16) * 32]);
        }
    };

    f32x4 acc[4][4] = {};

    stage(0, 0);
    __syncthreads();   // compiler drains vmcnt before the barrier

    int buf = 0;
    for (int t = 0; t < NT; ++t) {
        if (t + 1 < NT) stage(buf ^ 1, t + 1);

        const int g = l >> 4, r = l & 15;
        half8 af[4], bf[4];
        #pragma unroll
        for (int i = 0; i < 4; ++i)
            af[i] = *(const half8*)&Ab[buf][(wr * 64 + i * 16 + r) * 32 + g * 8];
        #pragma unroll
        for (int j = 0; j < 4; ++j)
            bf[j] = *(const half8*)&Bb[buf][(wc * 64 + j * 16 + r) * 32 + g * 8];

        #pragma unroll
        for (int i = 0; i < 4; ++i)
            #pragma unroll
            for (int j = 0; j < 4; ++j)
                acc[i][j] = __builtin_amdgcn_mfma_f32_16x16x32_f16(af[i], bf[j], acc[i][j], 0, 0, 0);

        __syncthreads();
        buf ^= 1;
    }

    // Epilogue: D row = (l>>4)*4+reg, col = l&15 (within 16x16 fragment)
    const int lg = l >> 4, lr = l & 15;
    #pragma unroll
    for (int i = 0; i < 4; ++i) {
        #pragma unroll
        for (int j = 0; j < 4; ++j) {
            const int n = n0 + wc * 64 + j * 16 + lr;
            const float bs = bias[n];
            #pragma unroll
            for (int rg = 0; rg < 4; ++rg) {
                const int m = m0 + wr * 64 + i * 16 + lg * 4 + rg;
                float v = acc[i][j][rg] + bs;
                v = v > 0.0f ? v : 0.0f;
                if constexpr (OUTF32)
                    ((float*)outp)[(size_t)m * Ntot + n] = v;
                else
                    ((_Float16*)outp)[(size_t)m * Ntot + n] = (_Float16)v;
            }
        }
    }
}

// ---------------------------------------------------------------------------
// Attention + PDG normalization + PV (fp32 VALU; f16 inputs from QKV buffer).
// QKV layout: [M][3072] f16, cols = qkv*1024 + h*128 + f.
// ---------------------------------------------------------------------------
__global__ __launch_bounds__(256, 2)
void attn_pdg(const _Float16* __restrict__ QKV, const float* __restrict__ Rel,
              _Float16* __restrict__ resh)
{
    __shared__ float pdg[S_][S_ + 1];
    __shared__ float stA[16][S_ + 4];
    __shared__ float stB[16][S_ + 4];
    __shared__ unsigned rbits[S_][4];
    __shared__ float inv_in[S_], inv_out[S_];

    const int tid = threadIdx.x;
    const int tx = tid & 15, ty = tid >> 4;
    const int b = blockIdx.x, h = blockIdx.y;
    const int wid = tid >> 6, lane = tid & 63;

    // Phase 0: relation bitmask via ballot (Rel entries are exact 0/1)
    for (int s = wid; s < S_; s += 4) {
        const float* row = &Rel[((size_t)b * S_ + s) * S_];
        unsigned long long b0 = __ballot(row[lane] > 0.5f);
        unsigned long long b1 = __ballot(row[64 + lane] > 0.5f);
        if (lane == 0) {
            rbits[s][0] = (unsigned)b0; rbits[s][1] = (unsigned)(b0 >> 32);
            rbits[s][2] = (unsigned)b1; rbits[s][3] = (unsigned)(b1 >> 32);
        }
    }

    const _Float16* Q = QKV + (size_t)(b * S_) * 3072 + h * DH_;
    const _Float16* K = Q + 1024;
    const _Float16* V = Q + 2048;

    // Phase 1: attn = Q K^T
    float acc[8][8] = {};
    for (int k0 = 0; k0 < DH_; k0 += 16) {
        const int row = tid >> 1, c0 = (tid & 1) * 8;
        union { uint4 u; _Float16 h[8]; } uq, uk;
        uq.u = *(const uint4*)&Q[(size_t)row * 3072 + k0 + c0];
        uk.u = *(const uint4*)&K[(size_t)row * 3072 + k0 + c0];
        #pragma unroll
        for (int j = 0; j < 8; ++j) {
            stA[c0 + j][row] = (float)uq.h[j];
            stB[c0 + j][row] = (float)uk.h[j];
        }
        __syncthreads();
        #pragma unroll
        for (int kk = 0; kk < 16; ++kk) {
            float a[8], bb[8];
            *reinterpret_cast<float4*>(&a[0])  = *reinterpret_cast<const float4*>(&stA[kk][ty * 8]);
            *reinterpret_cast<float4*>(&a[4])  = *reinterpret_cast<const float4*>(&stA[kk][ty * 8 + 4]);
            *reinterpret_cast<float4*>(&bb[0]) = *reinterpret_cast<const float4*>(&stB[kk][tx * 8]);
            *reinterpret_cast<float4*>(&bb[4]) = *reinterpret_cast<const float4*>(&stB[kk][tx * 8 + 4]);
            #pragma unroll
            for (int i = 0; i < 8; ++i)
                #pragma unroll
                for (int j = 0; j < 8; ++j)
                    acc[i][j] = fmaf(a[i], bb[j], acc[i][j]);
        }
        __syncthreads();
    }

    // Phase 2: pdg = rel*attn + eps into LDS
    #pragma unroll
    for (int i = 0; i < 8; ++i) {
        int s = ty * 8 + i;
        #pragma unroll
        for (int j = 0; j < 8; ++j) {
            int t = tx * 8 + j;
            float r;
            if (h < H_ / 2) {
                r = (float)((rbits[s][t >> 5] >> (t & 31)) & 1u);
                if (s == t) r += (float)h;
            } else {
                r = (float)((rbits[t][s >> 5] >> (s & 31)) & 1u);
            }
            pdg[s][t] = r * acc[i][j] + 1e-11f;
        }
    }
    __syncthreads();

    // Phase 3: degree sums
    if (tid < S_) {
        const int t = tid;
        float sum = 0.0f;
        for (int s = 0; s < S_; ++s) sum += pdg[s][t];
        inv_in[t] = 1.0f / sqrtf(sum);
    } else {
        const int s = tid - S_;
        float sum = 0.0f;
        for (int t = 0; t < S_; ++t) sum += pdg[s][t];
        inv_out[s] = 1.0f / sqrtf(sum);
    }
    __syncthreads();

    // Phase 4: softed (in-place in LDS)
    #pragma unroll
    for (int i = 0; i < 8; ++i) {
        int s = ty * 8 + i;
        #pragma unroll
        for (int j = 0; j < 8; ++j) {
            int t = tx * 8 + j;
            float r;
            if (h < H_ / 2) {
                r = (float)((rbits[s][t >> 5] >> (t & 31)) & 1u);
                if (s == t) r += (float)h;
            } else {
                r = (float)((rbits[t][s >> 5] >> (s & 31)) & 1u);
            }
            float p = r * acc[i][j] + 1e-11f;
            pdg[s][t] = r * p * inv_in[t] * inv_out[s];
        }
    }
    __syncthreads();

    // Phase 5: res = softed @ V
    float acc2[8][8] = {};
    for (int t0 = 0; t0 < S_; t0 += 16) {
        const int row = tid >> 4, c0 = (tid & 15) * 8;
        union { uint4 u; _Float16 h[8]; } uv;
        uv.u = *(const uint4*)&V[(size_t)(t0 + row) * 3072 + c0];
        #pragma unroll
        for (int j = 0; j < 8; ++j) stB[row][c0 + j] = (float)uv.h[j];
        __syncthreads();
        #pragma unroll
        for (int kk = 0; kk < 16; ++kk) {
            float a[8], bb[8];
            #pragma unroll
            for (int i = 0; i < 8; ++i) a[i] = pdg[ty * 8 + i][t0 + kk];
            *reinterpret_cast<float4*>(&bb[0]) = *reinterpret_cast<const float4*>(&stB[kk][tx * 8]);
            *reinterpret_cast<float4*>(&bb[4]) = *reinterpret_cast<const float4*>(&stB[kk][tx * 8 + 4]);
            #pragma unroll
            for (int i = 0; i < 8; ++i)
                #pragma unroll
                for (int j = 0; j < 8; ++j)
                    acc2[i][j] = fmaf(a[i], bb[j], acc2[i][j]);
        }
        __syncthreads();
    }

    // Phase 6: res -> resh f16 [M][1024], cols h*128 + f
    #pragma unroll
    for (int i = 0; i < 8; ++i) {
        int s = ty * 8 + i;
        half8 o;
        #pragma unroll
        for (int j = 0; j < 8; ++j) o[j] = (_Float16)acc2[i][j];
        *(half8*)&resh[(size_t)(b * S_ + s) * 1024 + h * DH_ + tx * 8] = o;
    }
}

// ---------------------------------------------------------------------------
extern "C" void kernel_launch(void* const* d_in, const int* in_sizes, int n_in,
                              void* d_out, int out_size, void* d_ws, size_t ws_size,
                              hipStream_t stream)
{
    const float* code = (const float*)d_in[0];
    const float* Rel  = (const float*)d_in[1];
    const float* Wq   = (const float*)d_in[2];
    const float* bq   = (const float*)d_in[3];
    const float* Wk   = (const float*)d_in[4];
    const float* bk   = (const float*)d_in[5];
    const float* Wv   = (const float*)d_in[6];
    const float* bv   = (const float*)d_in[7];
    const float* Wo   = (const float*)d_in[8];
    const float* bo   = (const float*)d_in[9];
    float* out = (float*)d_out;
    (void)in_sizes; (void)n_in; (void)out_size; (void)ws_size;

    // Workspace layout (bytes): ~346 MB total
    char* wsp = (char*)d_ws;
    _Float16* codeh = (_Float16*)wsp;  wsp += (size_t)M_ * 1024 * 2;
    _Float16* QKV   = (_Float16*)wsp;  wsp += (size_t)M_ * 3072 * 2;
    _Float16* resh  = (_Float16*)wsp;  wsp += (size_t)M_ * 1024 * 2;
    _Float16* Wt    = (_Float16*)wsp;  wsp += (size_t)3072 * 1024 * 2;
    _Float16* Wot   = (_Float16*)wsp;  wsp += (size_t)1024 * 2048 * 2;
    float* bias_all = (float*)wsp;     wsp += 3072 * 4;

    cvt_code<<<(M_ * 1024 / 8 + 255) / 256, 256, 0, stream>>>(code, codeh, M_ * 1024 / 8);
    cvt_wqkv<<<(3072 * 128 + 255) / 256, 256, 0, stream>>>(Wq, Wk, Wv, bq, bk, bv, Wt, bias_all);
    cvt_wo<<<(1024 * 256 + 255) / 256, 256, 0, stream>>>(Wo, Wot);

    // QKV projection: [M,1024] x [1024,3072] -> QKV f16 [M][3072]
    gemm_f16<false><<<dim3(M_ / 128, 24), 256, 0, stream>>>(
        codeh, codeh, 1024, Wt, bias_all, (void*)QKV, 3072, 1024);

    attn_pdg<<<dim3(B_, H_), 256, 0, stream>>>(QKV, Rel, resh);

    // Output projection: [M, 2048(=resh|codeh)] x [2048,1024] -> out f32
    gemm_f16<true><<<dim3(M_ / 128, 8), 256, 0, stream>>>(
        resh, codeh, 1024, Wot, bo, (void*)out, 1024, 2048);
}

// Round 4
// 661.881 us; speedup vs baseline: 6.7262x; 1.4731x over previous
//
#include <hip/hip_runtime.h>
#include <cstdint>
#include <cstddef>

// Problem constants
#define B_  256
#define S_  128
#define D_  1024
#define H_  8
#define DH_ 128
#define M_  (B_ * S_)   // 32768 rows

typedef _Float16 half8 __attribute__((ext_vector_type(8)));
typedef float    f32x4 __attribute__((ext_vector_type(4)));

#define GLOAD_LDS16(gp, lp)                                                    \
    __builtin_amdgcn_global_load_lds(                                          \
        (const __attribute__((address_space(1))) void*)(gp),                   \
        (__attribute__((address_space(3))) void*)(lp), 16, 0, 0)

// ---------------------------------------------------------------------------
// Conversion kernels
// ---------------------------------------------------------------------------
__global__ __launch_bounds__(256)
void cvt_code(const float* __restrict__ src, _Float16* __restrict__ dst, int n8)
{
    int i = blockIdx.x * 256 + threadIdx.x;
    if (i >= n8) return;
    const float4* s = (const float4*)src;
    float4 a = s[2 * i], b = s[2 * i + 1];
    half8 o;
    o[0] = (_Float16)a.x; o[1] = (_Float16)a.y; o[2] = (_Float16)a.z; o[3] = (_Float16)a.w;
    o[4] = (_Float16)b.x; o[5] = (_Float16)b.y; o[6] = (_Float16)b.z; o[7] = (_Float16)b.w;
    *(half8*)(dst + (size_t)i * 8) = o;
}

__global__ __launch_bounds__(256)
void cvt_wqkv(const float* __restrict__ Wq, const float* __restrict__ Wk,
              const float* __restrict__ Wv,
              const float* __restrict__ bq, const float* __restrict__ bk,
              const float* __restrict__ bv,
              _Float16* __restrict__ Wt, float* __restrict__ bias_all)
{
    int idx = blockIdx.x * 256 + threadIdx.x;   // 3072*128
    if (idx >= 3072 * 128) return;
    int n = idx >> 7, kc = idx & 127, k = kc * 8;
    int qkv = n >> 10, hf = n & 1023, h = hf >> 7, f = hf & 127;
    const float* W = (qkv == 0 ? Wq : (qkv == 1 ? Wk : Wv))
                     + (size_t)h * D_ * DH_ + (size_t)k * DH_ + f;
    half8 o;
    #pragma unroll
    for (int j = 0; j < 8; ++j) o[j] = (_Float16)W[(size_t)j * DH_];
    *(half8*)(Wt + (size_t)n * 1024 + k) = o;
    if (kc == 0)
        bias_all[n] = (qkv == 0 ? bq : (qkv == 1 ? bk : bv))[h * DH_ + f];
}

__global__ __launch_bounds__(256)
void cvt_wo(const float* __restrict__ Wo, _Float16* __restrict__ Wot)
{
    int idx = blockIdx.x * 256 + threadIdx.x;   // 1024*256
    if (idx >= 1024 * 256) return;
    int n = idx >> 8, kc = idx & 255, k = kc * 8;
    const float* W = Wo + (size_t)k * 1024 + n;
    half8 o;
    #pragma unroll
    for (int j = 0; j < 8; ++j) o[j] = (_Float16)W[(size_t)j * 1024];
    *(half8*)(Wot + (size_t)n * 2048 + k) = o;
}

// ---------------------------------------------------------------------------
// f16 MFMA GEMM (m97 structure), as validated in round 3.
// ---------------------------------------------------------------------------
template <bool OUTF32>
__global__ __launch_bounds__(256, 2)
void gemm_f16(const _Float16* __restrict__ A1, const _Float16* __restrict__ A2,
              int K1, const _Float16* __restrict__ Bt,
              const float* __restrict__ bias, void* __restrict__ outp,
              int Ntot, int Ktot)
{
    __shared__ _Float16 Ab[2][128 * 32];
    __shared__ _Float16 Bb[2][128 * 32];

    const int tid = threadIdx.x;
    const int w = tid >> 6, l = tid & 63;
    const int wr = w >> 1, wc = w & 1;
    const int m0 = blockIdx.x * 128, n0 = blockIdx.y * 128;
    const int NT = Ktot / 32;

    auto stage = [&](int buf, int t) {
        const int k0 = t * 32;
        const _Float16* Asrc; int kc;
        if (k0 < K1) { Asrc = A1; kc = k0; } else { Asrc = A2; kc = k0 - K1; }
        const int r = w * 32 + (l >> 2);
        const int c = (l & 3) * 8;
        #pragma unroll
        for (int i = 0; i < 2; ++i) {
            const _Float16* g = Asrc + (size_t)(m0 + r + i * 16) * 1024 + kc + c;
            GLOAD_LDS16(g, &Ab[buf][(w * 32 + i * 16) * 32]);
        }
        #pragma unroll
        for (int i = 0; i < 2; ++i) {
            const _Float16* g = Bt + (size_t)(n0 + r + i * 16) * Ktot + k0 + c;
            GLOAD_LDS16(g, &Bb[buf][(w * 32 + i * 16) * 32]);
        }
    };

    f32x4 acc[4][4] = {};

    stage(0, 0);
    __syncthreads();

    int buf = 0;
    for (int t = 0; t < NT; ++t) {
        if (t + 1 < NT) stage(buf ^ 1, t + 1);

        const int g = l >> 4, r = l & 15;
        half8 af[4], bf[4];
        #pragma unroll
        for (int i = 0; i < 4; ++i)
            af[i] = *(const half8*)&Ab[buf][(wr * 64 + i * 16 + r) * 32 + g * 8];
        #pragma unroll
        for (int j = 0; j < 4; ++j)
            bf[j] = *(const half8*)&Bb[buf][(wc * 64 + j * 16 + r) * 32 + g * 8];

        #pragma unroll
        for (int i = 0; i < 4; ++i)
            #pragma unroll
            for (int j = 0; j < 4; ++j)
                acc[i][j] = __builtin_amdgcn_mfma_f32_16x16x32_f16(af[i], bf[j], acc[i][j], 0, 0, 0);

        __syncthreads();
        buf ^= 1;
    }

    const int lg = l >> 4, lr = l & 15;
    #pragma unroll
    for (int i = 0; i < 4; ++i) {
        #pragma unroll
        for (int j = 0; j < 4; ++j) {
            const int n = n0 + wc * 64 + j * 16 + lr;
            const float bs = bias[n];
            #pragma unroll
            for (int rg = 0; rg < 4; ++rg) {
                const int m = m0 + wr * 64 + i * 16 + lg * 4 + rg;
                float v = acc[i][j][rg] + bs;
                v = v > 0.0f ? v : 0.0f;
                if constexpr (OUTF32)
                    ((float*)outp)[(size_t)m * Ntot + n] = v;
                else
                    ((_Float16*)outp)[(size_t)m * Ntot + n] = (_Float16)v;
            }
        }
    }
}

// ---------------------------------------------------------------------------
// MFMA attention + PDG normalization + PV.
// One block per (b,h); 4 waves in 2x2 over the 128x128 score tile.
// Scores stay in registers; degree sums via shfl butterflies; softed goes
// through a padded f16 LDS tile to become the PV A-operand; V transposed
// per k-step into padded LDS.
// ---------------------------------------------------------------------------
#define PPAD 136   // P row stride (f16): 272B, 16B-aligned, 2-way banks
#define VPAD 40    // Vt row stride (f16): 80B,  16B-aligned, ~2-way banks

__global__ __launch_bounds__(256, 2)
void attn_pdg_mfma(const _Float16* __restrict__ QKV, const float* __restrict__ Rel,
                   _Float16* __restrict__ resh)
{
    __shared__ __align__(16) char smem[72704];
    _Float16* P     = (_Float16*)smem;                     // 128*136*2 = 34816
    _Float16* Qs    = (_Float16*)(smem + 34816);           // [2][128*32] = 16384
    _Float16* Ks    = Qs + 2 * 4096;                       // [2][128*32] = 16384
    _Float16* Vt    = (_Float16*)(smem + 34816);           // [128*40] aliases Qs/Ks
    unsigned* rbits = (unsigned*)(smem + 67584);           // [128][4]    = 2048
    float* rowpart  = (float*)(smem + 69632);              // [2][128]    = 1024
    float* colpart  = (float*)(smem + 70656);              // [2][128]    = 1024
    float* inv_in   = (float*)(smem + 71680);              // [128]       = 512
    float* inv_out  = (float*)(smem + 72192);              // [128]       = 512

    const int tid = threadIdx.x;
    const int w = tid >> 6, l = tid & 63;
    const int wr = w >> 1, wc = w & 1;
    const int lr = l & 15, lg = l >> 4;
    const int b = blockIdx.x, h = blockIdx.y;

    // Phase 0: relation bitmask (Rel entries are exact 0/1)
    for (int s = w; s < S_; s += 4) {
        const float* row = &Rel[((size_t)b * S_ + s) * S_];
        unsigned long long b0 = __ballot(row[l] > 0.5f);
        unsigned long long b1 = __ballot(row[64 + l] > 0.5f);
        if (l == 0) {
            rbits[s * 4 + 0] = (unsigned)b0; rbits[s * 4 + 1] = (unsigned)(b0 >> 32);
            rbits[s * 4 + 2] = (unsigned)b1; rbits[s * 4 + 3] = (unsigned)(b1 >> 32);
        }
    }

    const size_t gbase = (size_t)(b * S_) * 3072 + h * DH_;

    // --- Phase 1: attn = Q K^T via MFMA, global_load_lds double-buffered ---
    auto stageQK = [&](int bufi, int t) {
        const int k0 = t * 32;
        const int rr = l >> 2, cc = (l & 3) * 8;
        #pragma unroll
        for (int i = 0; i < 2; ++i) {
            const int row = w * 32 + i * 16;
            const _Float16* gq = QKV + gbase + (size_t)(row + rr) * 3072 + k0 + cc;
            GLOAD_LDS16(gq, Qs + bufi * 4096 + row * 32);
            const _Float16* gk = QKV + gbase + 1024 + (size_t)(row + rr) * 3072 + k0 + cc;
            GLOAD_LDS16(gk, Ks + bufi * 4096 + row * 32);
        }
    };

    f32x4 acc[4][4] = {};
    stageQK(0, 0);
    __syncthreads();
    int buf = 0;
    for (int t = 0; t < 4; ++t) {
        if (t < 3) stageQK(buf ^ 1, t + 1);
        half8 af[4], bf[4];
        #pragma unroll
        for (int i = 0; i < 4; ++i)
            af[i] = *(const half8*)&Qs[buf * 4096 + (wr * 64 + i * 16 + lr) * 32 + lg * 8];
        #pragma unroll
        for (int j = 0; j < 4; ++j)
            bf[j] = *(const half8*)&Ks[buf * 4096 + (wc * 64 + j * 16 + lr) * 32 + lg * 8];
        #pragma unroll
        for (int i = 0; i < 4; ++i)
            #pragma unroll
            for (int j = 0; j < 4; ++j)
                acc[i][j] = __builtin_amdgcn_mfma_f32_16x16x32_f16(af[i], bf[j], acc[i][j], 0, 0, 0);
        __syncthreads();
        buf ^= 1;
    }

    // --- Phase 2: p = rel*attn + eps in registers ---
    auto relf = [&](int s, int t) -> float {
        float r;
        if (h < H_ / 2) {
            r = (float)((rbits[s * 4 + (t >> 5)] >> (t & 31)) & 1u);
            if (s == t) r += (float)h;
        } else {
            r = (float)((rbits[t * 4 + (s >> 5)] >> (s & 31)) & 1u);
        }
        return r;
    };

    f32x4 p[4][4];
    #pragma unroll
    for (int i = 0; i < 4; ++i)
        #pragma unroll
        for (int j = 0; j < 4; ++j)
            #pragma unroll
            for (int rg = 0; rg < 4; ++rg) {
                const int s = wr * 64 + i * 16 + lg * 4 + rg;
                const int t = wc * 64 + j * 16 + lr;
                p[i][j][rg] = relf(s, t) * acc[i][j][rg] + 1e-11f;
            }

    // --- Phase 3: degree sums via shfl butterflies ---
    // Row sums (outdeg): reduce over t = (j, lr)
    #pragma unroll
    for (int i = 0; i < 4; ++i)
        #pragma unroll
        for (int rg = 0; rg < 4; ++rg) {
            float part = p[i][0][rg] + p[i][1][rg] + p[i][2][rg] + p[i][3][rg];
            part += __shfl_xor(part, 1);
            part += __shfl_xor(part, 2);
            part += __shfl_xor(part, 4);
            part += __shfl_xor(part, 8);
            if (lr == 0) rowpart[wc * 128 + wr * 64 + i * 16 + lg * 4 + rg] = part;
        }
    // Col sums (indeg): reduce over s = (i, lg, rg)
    #pragma unroll
    for (int j = 0; j < 4; ++j) {
        float part = 0.0f;
        #pragma unroll
        for (int i = 0; i < 4; ++i)
            part += p[i][j][0] + p[i][j][1] + p[i][j][2] + p[i][j][3];
        part += __shfl_xor(part, 16);
        part += __shfl_xor(part, 32);
        if (lg == 0) colpart[wr * 128 + wc * 64 + j * 16 + lr] = part;
    }
    __syncthreads();

    if (tid < 128) {
        inv_in[tid] = rsqrtf(colpart[tid] + colpart[128 + tid]);
    } else {
        const int s = tid - 128;
        inv_out[s] = rsqrtf(rowpart[s] + rowpart[128 + s]);
    }
    __syncthreads();

    // --- Phase 4: softed -> f16 LDS tile P[s][t] ---
    float itj[4];
    #pragma unroll
    for (int j = 0; j < 4; ++j) itj[j] = inv_in[wc * 64 + j * 16 + lr];
    #pragma unroll
    for (int i = 0; i < 4; ++i)
        #pragma unroll
        for (int rg = 0; rg < 4; ++rg) {
            const int s = wr * 64 + i * 16 + lg * 4 + rg;
            const float os = inv_out[s];
            #pragma unroll
            for (int j = 0; j < 4; ++j) {
                const int t = wc * 64 + j * 16 + lr;
                const float val = relf(s, t) * p[i][j][rg] * itj[j] * os;
                P[s * PPAD + t] = (_Float16)val;
            }
        }

    // --- Phase 5: res = softed @ V ---
    const _Float16* Vb = QKV + gbase + 2048;
    uint4 vreg[2];
    auto loadV = [&](int t) {
        #pragma unroll
        for (int ii = 0; ii < 2; ++ii) {
            const int unit = tid + ii * 256;
            const int tt = unit & 31, fg = unit >> 5;
            vreg[ii] = *(const uint4*)&Vb[(size_t)(t * 32 + tt) * 3072 + fg * 8];
        }
    };

    loadV(0);
    f32x4 acc2[4][4] = {};
    for (int t = 0; t < 4; ++t) {
        // transpose-stage V chunk from regs
        #pragma unroll
        for (int ii = 0; ii < 2; ++ii) {
            union { uint4 u; _Float16 hh[8]; } uu;
            uu.u = vreg[ii];
            const int unit = tid + ii * 256;
            const int tt = unit & 31, fg = unit >> 5;
            #pragma unroll
            for (int e = 0; e < 8; ++e)
                Vt[(fg * 8 + e) * VPAD + tt] = uu.hh[e];
        }
        __syncthreads();
        if (t < 3) loadV(t + 1);

        half8 af[4], bf[4];
        #pragma unroll
        for (int i = 0; i < 4; ++i)
            af[i] = *(const half8*)&P[(wr * 64 + i * 16 + lr) * PPAD + t * 32 + lg * 8];
        #pragma unroll
        for (int j = 0; j < 4; ++j)
            bf[j] = *(const half8*)&Vt[(wc * 64 + j * 16 + lr) * VPAD + lg * 8];
        #pragma unroll
        for (int i = 0; i < 4; ++i)
            #pragma unroll
            for (int j = 0; j < 4; ++j)
                acc2[i][j] = __builtin_amdgcn_mfma_f32_16x16x32_f16(af[i], bf[j], acc2[i][j], 0, 0, 0);
        __syncthreads();
    }

    // --- Phase 6: write resh[b*S+s][h*128 + f] ---
    #pragma unroll
    for (int i = 0; i < 4; ++i)
        #pragma unroll
        for (int rg = 0; rg < 4; ++rg) {
            const int s = wr * 64 + i * 16 + lg * 4 + rg;
            #pragma unroll
            for (int j = 0; j < 4; ++j) {
                const int f = wc * 64 + j * 16 + lr;
                resh[((size_t)(b * S_ + s)) * 1024 + h * DH_ + f] = (_Float16)acc2[i][j][rg];
            }
        }
}

// ---------------------------------------------------------------------------
extern "C" void kernel_launch(void* const* d_in, const int* in_sizes, int n_in,
                              void* d_out, int out_size, void* d_ws, size_t ws_size,
                              hipStream_t stream)
{
    const float* code = (const float*)d_in[0];
    const float* Rel  = (const float*)d_in[1];
    const float* Wq   = (const float*)d_in[2];
    const float* bq   = (const float*)d_in[3];
    const float* Wk   = (const float*)d_in[4];
    const float* bk   = (const float*)d_in[5];
    const float* Wv   = (const float*)d_in[6];
    const float* bv   = (const float*)d_in[7];
    const float* Wo   = (const float*)d_in[8];
    const float* bo   = (const float*)d_in[9];
    float* out = (float*)d_out;
    (void)in_sizes; (void)n_in; (void)out_size; (void)ws_size;

    char* wsp = (char*)d_ws;
    _Float16* codeh = (_Float16*)wsp;  wsp += (size_t)M_ * 1024 * 2;
    _Float16* QKV   = (_Float16*)wsp;  wsp += (size_t)M_ * 3072 * 2;
    _Float16* resh  = (_Float16*)wsp;  wsp += (size_t)M_ * 1024 * 2;
    _Float16* Wt    = (_Float16*)wsp;  wsp += (size_t)3072 * 1024 * 2;
    _Float16* Wot   = (_Float16*)wsp;  wsp += (size_t)1024 * 2048 * 2;
    float* bias_all = (float*)wsp;     wsp += 3072 * 4;

    cvt_code<<<(M_ * 1024 / 8 + 255) / 256, 256, 0, stream>>>(code, codeh, M_ * 1024 / 8);
    cvt_wqkv<<<(3072 * 128 + 255) / 256, 256, 0, stream>>>(Wq, Wk, Wv, bq, bk, bv, Wt, bias_all);
    cvt_wo<<<(1024 * 256 + 255) / 256, 256, 0, stream>>>(Wo, Wot);

    gemm_f16<false><<<dim3(M_ / 128, 24), 256, 0, stream>>>(
        codeh, codeh, 1024, Wt, bias_all, (void*)QKV, 3072, 1024);

    attn_pdg_mfma<<<dim3(B_, H_), 256, 0, stream>>>(QKV, Rel, resh);

    gemm_f16<true><<<dim3(M_ / 128, 8), 256, 0, stream>>>(
        resh, codeh, 1024, Wot, bo, (void*)out, 1024, 2048);
}

// Round 5
// 568.147 us; speedup vs baseline: 7.8359x; 1.1650x over previous
//
#include <hip/hip_runtime.h>
#include <cstdint>
#include <cstddef>

// Problem constants
#define B_  256
#define S_  128
#define D_  1024
#define H_  8
#define DH_ 128
#define M_  (B_ * S_)   // 32768 rows

typedef _Float16 half8 __attribute__((ext_vector_type(8)));
typedef float    f32x4 __attribute__((ext_vector_type(4)));

#define GLOAD_LDS16(gp, lp)                                                    \
    __builtin_amdgcn_global_load_lds(                                          \
        (const __attribute__((address_space(1))) void*)(gp),                   \
        (__attribute__((address_space(3))) void*)(lp), 16, 0, 0)

// ---------------------------------------------------------------------------
// Conversion kernels
// ---------------------------------------------------------------------------
__global__ __launch_bounds__(256)
void cvt_code(const float* __restrict__ src, _Float16* __restrict__ dst, int n8)
{
    int i = blockIdx.x * 256 + threadIdx.x;
    if (i >= n8) return;
    const float4* s = (const float4*)src;
    float4 a = s[2 * i], b = s[2 * i + 1];
    half8 o;
    o[0] = (_Float16)a.x; o[1] = (_Float16)a.y; o[2] = (_Float16)a.z; o[3] = (_Float16)a.w;
    o[4] = (_Float16)b.x; o[5] = (_Float16)b.y; o[6] = (_Float16)b.z; o[7] = (_Float16)b.w;
    *(half8*)(dst + (size_t)i * 8) = o;
}

__global__ __launch_bounds__(256)
void cvt_wqkv(const float* __restrict__ Wq, const float* __restrict__ Wk,
              const float* __restrict__ Wv,
              const float* __restrict__ bq, const float* __restrict__ bk,
              const float* __restrict__ bv,
              _Float16* __restrict__ Wt, float* __restrict__ bias_all)
{
    int idx = blockIdx.x * 256 + threadIdx.x;   // 3072*128
    if (idx >= 3072 * 128) return;
    int n = idx >> 7, kc = idx & 127, k = kc * 8;
    int qkv = n >> 10, hf = n & 1023, h = hf >> 7, f = hf & 127;
    const float* W = (qkv == 0 ? Wq : (qkv == 1 ? Wk : Wv))
                     + (size_t)h * D_ * DH_ + (size_t)k * DH_ + f;
    half8 o;
    #pragma unroll
    for (int j = 0; j < 8; ++j) o[j] = (_Float16)W[(size_t)j * DH_];
    *(half8*)(Wt + (size_t)n * 1024 + k) = o;
    if (kc == 0)
        bias_all[n] = (qkv == 0 ? bq : (qkv == 1 ? bk : bv))[h * DH_ + f];
}

__global__ __launch_bounds__(256)
void cvt_wo(const float* __restrict__ Wo, _Float16* __restrict__ Wot)
{
    int idx = blockIdx.x * 256 + threadIdx.x;   // 1024*256
    if (idx >= 1024 * 256) return;
    int n = idx >> 8, kc = idx & 255, k = kc * 8;
    const float* W = Wo + (size_t)k * 1024 + n;
    half8 o;
    #pragma unroll
    for (int j = 0; j < 8; ++j) o[j] = (_Float16)W[(size_t)j * 1024];
    *(half8*)(Wot + (size_t)n * 2048 + k) = o;
}

// ---------------------------------------------------------------------------
// 256x256 8-phase f16 MFMA GEMM (m201-style port, plain HIP).
// BK=64, 8 waves (2M x 4N), 512 threads, 128 KiB LDS double buffer.
// Interleaved wave tiling: A-frag rows = fi*32 + wm*16 + lr (fi 0..7),
// B-frag cols = fj*64 + wn*16 + lr (fj 0..3) -> phase (qm,qn) touches one
// A-half and one B-half uniformly across waves.
// Granule swizzle: LDS granule pos = src_granule ^ (row&7); writes stay
// linear (global_load_lds), source column pre-swizzled, reads apply XOR.
// Per tile: stage order [A0,B0,B1,A1]; vmcnt(4) at P0/P1/P2 (counted, loads
// span barriers); drain only on the last tile.
// A = [A1p | A2p] virtual concat along K at seam K1 (row stride 1024 both).
// Bt is B^T: [Ntot][Ktot] f16.
// ---------------------------------------------------------------------------
template <bool OUTF32>
__global__ __launch_bounds__(512, 1)
void gemm_f16_8p(const _Float16* __restrict__ A1p, const _Float16* __restrict__ A2p,
                 int K1, const _Float16* __restrict__ Bt,
                 const float* __restrict__ bias, void* __restrict__ outp,
                 int Ntot, int Ktot, int ntn)
{
    __shared__ __align__(16) char lds[131072];

    const int tid = threadIdx.x;
    const int w = tid >> 6, l = tid & 63;
    const int wm = w >> 2, wn = w & 3;
    const int lr = l & 15, lg = l >> 4;

    // Bijective XCD swizzle (gridDim.x % 8 == 0), n-fastest decode.
    const int cpx = gridDim.x >> 3;
    const int bid = blockIdx.x;
    const int swz = (bid & 7) * cpx + (bid >> 3);
    const int m0 = (swz / ntn) * 256, n0 = (swz % ntn) * 256;

    const int NT = Ktot >> 6;

    // staging lane geometry
    const int srow  = l >> 3;                   // row within 8-row chunk
    const int sgcol = ((l & 7) ^ srow) * 8;     // pre-swizzled source col (f16)

    // half: 0=A0, 1=B0, 2=B1, 3=A1
    auto stageHalf = [&](int bufi, int t, int half) {
        const int k0 = t << 6;
        const bool isA = (half == 0) || (half == 3);
        const int hh = (half >= 2) ? 1 : 0;
        char* dst0 = lds + bufi * 65536 + (isA ? 0 : 32768) + hh * 16384;
        if (isA) {
            const _Float16* Asrc; int kc;
            if (k0 < K1) { Asrc = A1p; kc = k0; } else { Asrc = A2p; kc = k0 - K1; }
            #pragma unroll
            for (int i = 0; i < 2; ++i) {
                const int c = i * 8 + w;
                const int row = hh * 128 + c * 8 + srow;
                const _Float16* g = Asrc + (size_t)(m0 + row) * 1024 + kc + sgcol;
                GLOAD_LDS16(g, dst0 + c * 1024);
            }
        } else {
            #pragma unroll
            for (int i = 0; i < 2; ++i) {
                const int c = i * 8 + w;
                const int row = hh * 128 + c * 8 + srow;
                const _Float16* g = Bt + (size_t)(n0 + row) * Ktot + k0 + sgcol;
                GLOAD_LDS16(g, dst0 + c * 1024);
            }
        }
    };

    auto ldA = [&](int bufi, int fi, int ks) -> half8 {
        const int row = fi * 32 + wm * 16 + lr;
        const int pos = (ks * 4 + lg) ^ (row & 7);
        return *(const half8*)(lds + bufi * 65536 + row * 128 + pos * 16);
    };
    auto ldB = [&](int bufi, int fj, int ks) -> half8 {
        const int row = fj * 64 + wn * 16 + lr;
        const int pos = (ks * 4 + lg) ^ (row & 7);
        return *(const half8*)(lds + bufi * 65536 + 32768 + row * 128 + pos * 16);
    };

    f32x4 acc[8][4] = {};
    half8 aq[4][2], b0[2][2], b1[2][2];

    // Prologue: stage tile 0 (order A0,B0,B1,A1)
    stageHalf(0, 0, 0); stageHalf(0, 0, 1); stageHalf(0, 0, 2); stageHalf(0, 0, 3);

    for (int t = 0; t < NT; ++t) {
        const int buf = t & 1;
        const bool nl = (t + 1 < NT);

        // ---- P0: quadrant (qm0, qn0). Needs A0,B0 of tile t.
        asm volatile("s_waitcnt vmcnt(4)" ::: "memory");
        __builtin_amdgcn_s_barrier();
        #pragma unroll
        for (int fi = 0; fi < 4; ++fi)
            #pragma unroll
            for (int ks = 0; ks < 2; ++ks)
                aq[fi][ks] = ldA(buf, fi, ks);
        #pragma unroll
        for (int fj = 0; fj < 2; ++fj)
            #pragma unroll
            for (int ks = 0; ks < 2; ++ks)
                b0[fj][ks] = ldB(buf, fj, ks);
        if (nl) stageHalf(buf ^ 1, t + 1, 0);
        asm volatile("s_waitcnt lgkmcnt(0)" ::: "memory");
        __builtin_amdgcn_sched_barrier(0);
        __builtin_amdgcn_s_setprio(1);
        #pragma unroll
        for (int ks = 0; ks < 2; ++ks)
            #pragma unroll
            for (int fi = 0; fi < 4; ++fi)
                #pragma unroll
                for (int fj = 0; fj < 2; ++fj)
                    acc[fi][fj] = __builtin_amdgcn_mfma_f32_16x16x32_f16(
                        aq[fi][ks], b0[fj][ks], acc[fi][fj], 0, 0, 0);
        __builtin_amdgcn_s_setprio(0);
        __builtin_amdgcn_s_barrier();

        // ---- P1: quadrant (qm0, qn1). Needs B1 of tile t.
        if (nl) asm volatile("s_waitcnt vmcnt(4)" ::: "memory");
        else    asm volatile("s_waitcnt vmcnt(2)" ::: "memory");
        __builtin_amdgcn_s_barrier();
        #pragma unroll
        for (int fj = 0; fj < 2; ++fj)
            #pragma unroll
            for (int ks = 0; ks < 2; ++ks)
                b1[fj][ks] = ldB(buf, fj + 2, ks);
        if (nl) stageHalf(buf ^ 1, t + 1, 1);
        asm volatile("s_waitcnt lgkmcnt(0)" ::: "memory");
        __builtin_amdgcn_sched_barrier(0);
        __builtin_amdgcn_s_setprio(1);
        #pragma unroll
        for (int ks = 0; ks < 2; ++ks)
            #pragma unroll
            for (int fi = 0; fi < 4; ++fi)
                #pragma unroll
                for (int fj = 0; fj < 2; ++fj)
                    acc[fi][fj + 2] = __builtin_amdgcn_mfma_f32_16x16x32_f16(
                        aq[fi][ks], b1[fj][ks], acc[fi][fj + 2], 0, 0, 0);
        __builtin_amdgcn_s_setprio(0);
        __builtin_amdgcn_s_barrier();

        // ---- P2: quadrant (qm1, qn1). Needs A1 of tile t.
        if (nl) asm volatile("s_waitcnt vmcnt(4)" ::: "memory");
        else    asm volatile("s_waitcnt vmcnt(0)" ::: "memory");
        __builtin_amdgcn_s_barrier();
        #pragma unroll
        for (int fi = 0; fi < 4; ++fi)
            #pragma unroll
            for (int ks = 0; ks < 2; ++ks)
                aq[fi][ks] = ldA(buf, fi + 4, ks);
        if (nl) stageHalf(buf ^ 1, t + 1, 2);
        asm volatile("s_waitcnt lgkmcnt(0)" ::: "memory");
        __builtin_amdgcn_sched_barrier(0);
        __builtin_amdgcn_s_setprio(1);
        #pragma unroll
        for (int ks = 0; ks < 2; ++ks)
            #pragma unroll
            for (int fi = 0; fi < 4; ++fi)
                #pragma unroll
                for (int fj = 0; fj < 2; ++fj)
                    acc[fi + 4][fj + 2] = __builtin_amdgcn_mfma_f32_16x16x32_f16(
                        aq[fi][ks], b1[fj][ks], acc[fi + 4][fj + 2], 0, 0, 0);
        __builtin_amdgcn_s_setprio(0);
        __builtin_amdgcn_s_barrier();

        // ---- P3: quadrant (qm1, qn0). Reuses aq (qm1) and b0 regs.
        if (nl) stageHalf(buf ^ 1, t + 1, 3);
        __builtin_amdgcn_s_setprio(1);
        #pragma unroll
        for (int ks = 0; ks < 2; ++ks)
            #pragma unroll
            for (int fi = 0; fi < 4; ++fi)
                #pragma unroll
                for (int fj = 0; fj < 2; ++fj)
                    acc[fi + 4][fj] = __builtin_amdgcn_mfma_f32_16x16x32_f16(
                        aq[fi][ks], b0[fj][ks], acc[fi + 4][fj], 0, 0, 0);
        __builtin_amdgcn_s_setprio(0);
        __builtin_amdgcn_s_barrier();
    }

    // Epilogue: bias + relu + store
    #pragma unroll
    for (int fi = 0; fi < 8; ++fi) {
        #pragma unroll
        for (int fj = 0; fj < 4; ++fj) {
            const int n = n0 + fj * 64 + wn * 16 + lr;
            const float bs = bias[n];
            #pragma unroll
            for (int rg = 0; rg < 4; ++rg) {
                const int m = m0 + fi * 32 + wm * 16 + lg * 4 + rg;
                float v = acc[fi][fj][rg] + bs;
                v = v > 0.0f ? v : 0.0f;
                if constexpr (OUTF32)
                    ((float*)outp)[(size_t)m * Ntot + n] = v;
                else
                    ((_Float16*)outp)[(size_t)m * Ntot + n] = (_Float16)v;
            }
        }
    }
}

// ---------------------------------------------------------------------------
// MFMA attention + PDG normalization + PV (validated round 4; unchanged).
// ---------------------------------------------------------------------------
#define PPAD 136
#define VPAD 40

__global__ __launch_bounds__(256, 2)
void attn_pdg_mfma(const _Float16* __restrict__ QKV, const float* __restrict__ Rel,
                   _Float16* __restrict__ resh)
{
    __shared__ __align__(16) char smem[72704];
    _Float16* P     = (_Float16*)smem;
    _Float16* Qs    = (_Float16*)(smem + 34816);
    _Float16* Ks    = Qs + 2 * 4096;
    _Float16* Vt    = (_Float16*)(smem + 34816);
    unsigned* rbits = (unsigned*)(smem + 67584);
    float* rowpart  = (float*)(smem + 69632);
    float* colpart  = (float*)(smem + 70656);
    float* inv_in   = (float*)(smem + 71680);
    float* inv_out  = (float*)(smem + 72192);

    const int tid = threadIdx.x;
    const int w = tid >> 6, l = tid & 63;
    const int wr = w >> 1, wc = w & 1;
    const int lr = l & 15, lg = l >> 4;
    const int b = blockIdx.x, h = blockIdx.y;

    for (int s = w; s < S_; s += 4) {
        const float* row = &Rel[((size_t)b * S_ + s) * S_];
        unsigned long long b0 = __ballot(row[l] > 0.5f);
        unsigned long long b1 = __ballot(row[64 + l] > 0.5f);
        if (l == 0) {
            rbits[s * 4 + 0] = (unsigned)b0; rbits[s * 4 + 1] = (unsigned)(b0 >> 32);
            rbits[s * 4 + 2] = (unsigned)b1; rbits[s * 4 + 3] = (unsigned)(b1 >> 32);
        }
    }

    const size_t gbase = (size_t)(b * S_) * 3072 + h * DH_;

    auto stageQK = [&](int bufi, int t) {
        const int k0 = t * 32;
        const int rr = l >> 2, cc = (l & 3) * 8;
        #pragma unroll
        for (int i = 0; i < 2; ++i) {
            const int row = w * 32 + i * 16;
            const _Float16* gq = QKV + gbase + (size_t)(row + rr) * 3072 + k0 + cc;
            GLOAD_LDS16(gq, Qs + bufi * 4096 + row * 32);
            const _Float16* gk = QKV + gbase + 1024 + (size_t)(row + rr) * 3072 + k0 + cc;
            GLOAD_LDS16(gk, Ks + bufi * 4096 + row * 32);
        }
    };

    f32x4 acc[4][4] = {};
    stageQK(0, 0);
    __syncthreads();
    int buf = 0;
    for (int t = 0; t < 4; ++t) {
        if (t < 3) stageQK(buf ^ 1, t + 1);
        half8 af[4], bf[4];
        #pragma unroll
        for (int i = 0; i < 4; ++i)
            af[i] = *(const half8*)&Qs[buf * 4096 + (wr * 64 + i * 16 + lr) * 32 + lg * 8];
        #pragma unroll
        for (int j = 0; j < 4; ++j)
            bf[j] = *(const half8*)&Ks[buf * 4096 + (wc * 64 + j * 16 + lr) * 32 + lg * 8];
        #pragma unroll
        for (int i = 0; i < 4; ++i)
            #pragma unroll
            for (int j = 0; j < 4; ++j)
                acc[i][j] = __builtin_amdgcn_mfma_f32_16x16x32_f16(af[i], bf[j], acc[i][j], 0, 0, 0);
        __syncthreads();
        buf ^= 1;
    }

    auto relf = [&](int s, int t) -> float {
        float r;
        if (h < H_ / 2) {
            r = (float)((rbits[s * 4 + (t >> 5)] >> (t & 31)) & 1u);
            if (s == t) r += (float)h;
        } else {
            r = (float)((rbits[t * 4 + (s >> 5)] >> (s & 31)) & 1u);
        }
        return r;
    };

    f32x4 p[4][4];
    #pragma unroll
    for (int i = 0; i < 4; ++i)
        #pragma unroll
        for (int j = 0; j < 4; ++j)
            #pragma unroll
            for (int rg = 0; rg < 4; ++rg) {
                const int s = wr * 64 + i * 16 + lg * 4 + rg;
                const int t = wc * 64 + j * 16 + lr;
                p[i][j][rg] = relf(s, t) * acc[i][j][rg] + 1e-11f;
            }

    #pragma unroll
    for (int i = 0; i < 4; ++i)
        #pragma unroll
        for (int rg = 0; rg < 4; ++rg) {
            float part = p[i][0][rg] + p[i][1][rg] + p[i][2][rg] + p[i][3][rg];
            part += __shfl_xor(part, 1);
            part += __shfl_xor(part, 2);
            part += __shfl_xor(part, 4);
            part += __shfl_xor(part, 8);
            if (lr == 0) rowpart[wc * 128 + wr * 64 + i * 16 + lg * 4 + rg] = part;
        }
    #pragma unroll
    for (int j = 0; j < 4; ++j) {
        float part = 0.0f;
        #pragma unroll
        for (int i = 0; i < 4; ++i)
            part += p[i][j][0] + p[i][j][1] + p[i][j][2] + p[i][j][3];
        part += __shfl_xor(part, 16);
        part += __shfl_xor(part, 32);
        if (lg == 0) colpart[wr * 128 + wc * 64 + j * 16 + lr] = part;
    }
    __syncthreads();

    if (tid < 128) {
        inv_in[tid] = rsqrtf(colpart[tid] + colpart[128 + tid]);
    } else {
        const int s = tid - 128;
        inv_out[s] = rsqrtf(rowpart[s] + rowpart[128 + s]);
    }
    __syncthreads();

    float itj[4];
    #pragma unroll
    for (int j = 0; j < 4; ++j) itj[j] = inv_in[wc * 64 + j * 16 + lr];
    #pragma unroll
    for (int i = 0; i < 4; ++i)
        #pragma unroll
        for (int rg = 0; rg < 4; ++rg) {
            const int s = wr * 64 + i * 16 + lg * 4 + rg;
            const float os = inv_out[s];
            #pragma unroll
            for (int j = 0; j < 4; ++j) {
                const int t = wc * 64 + j * 16 + lr;
                const float val = relf(s, t) * p[i][j][rg] * itj[j] * os;
                P[s * PPAD + t] = (_Float16)val;
            }
        }

    const _Float16* Vb = QKV + gbase + 2048;
    uint4 vreg[2];
    auto loadV = [&](int t) {
        #pragma unroll
        for (int ii = 0; ii < 2; ++ii) {
            const int unit = tid + ii * 256;
            const int tt = unit & 31, fg = unit >> 5;
            vreg[ii] = *(const uint4*)&Vb[(size_t)(t * 32 + tt) * 3072 + fg * 8];
        }
    };

    loadV(0);
    f32x4 acc2[4][4] = {};
    for (int t = 0; t < 4; ++t) {
        #pragma unroll
        for (int ii = 0; ii < 2; ++ii) {
            union { uint4 u; _Float16 hh[8]; } uu;
            uu.u = vreg[ii];
            const int unit = tid + ii * 256;
            const int tt = unit & 31, fg = unit >> 5;
            #pragma unroll
            for (int e = 0; e < 8; ++e)
                Vt[(fg * 8 + e) * VPAD + tt] = uu.hh[e];
        }
        __syncthreads();
        if (t < 3) loadV(t + 1);

        half8 af[4], bf[4];
        #pragma unroll
        for (int i = 0; i < 4; ++i)
            af[i] = *(const half8*)&P[(wr * 64 + i * 16 + lr) * PPAD + t * 32 + lg * 8];
        #pragma unroll
        for (int j = 0; j < 4; ++j)
            bf[j] = *(const half8*)&Vt[(wc * 64 + j * 16 + lr) * VPAD + lg * 8];
        #pragma unroll
        for (int i = 0; i < 4; ++i)
            #pragma unroll
            for (int j = 0; j < 4; ++j)
                acc2[i][j] = __builtin_amdgcn_mfma_f32_16x16x32_f16(af[i], bf[j], acc2[i][j], 0, 0, 0);
        __syncthreads();
    }

    #pragma unroll
    for (int i = 0; i < 4; ++i)
        #pragma unroll
        for (int rg = 0; rg < 4; ++rg) {
            const int s = wr * 64 + i * 16 + lg * 4 + rg;
            #pragma unroll
            for (int j = 0; j < 4; ++j) {
                const int f = wc * 64 + j * 16 + lr;
                resh[((size_t)(b * S_ + s)) * 1024 + h * DH_ + f] = (_Float16)acc2[i][j][rg];
            }
        }
}

// ---------------------------------------------------------------------------
extern "C" void kernel_launch(void* const* d_in, const int* in_sizes, int n_in,
                              void* d_out, int out_size, void* d_ws, size_t ws_size,
                              hipStream_t stream)
{
    const float* code = (const float*)d_in[0];
    const float* Rel  = (const float*)d_in[1];
    const float* Wq   = (const float*)d_in[2];
    const float* bq   = (const float*)d_in[3];
    const float* Wk   = (const float*)d_in[4];
    const float* bk   = (const float*)d_in[5];
    const float* Wv   = (const float*)d_in[6];
    const float* bv   = (const float*)d_in[7];
    const float* Wo   = (const float*)d_in[8];
    const float* bo   = (const float*)d_in[9];
    float* out = (float*)d_out;
    (void)in_sizes; (void)n_in; (void)out_size; (void)ws_size;

    char* wsp = (char*)d_ws;
    _Float16* codeh = (_Float16*)wsp;  wsp += (size_t)M_ * 1024 * 2;
    _Float16* QKV   = (_Float16*)wsp;  wsp += (size_t)M_ * 3072 * 2;
    _Float16* resh  = (_Float16*)wsp;  wsp += (size_t)M_ * 1024 * 2;
    _Float16* Wt    = (_Float16*)wsp;  wsp += (size_t)3072 * 1024 * 2;
    _Float16* Wot   = (_Float16*)wsp;  wsp += (size_t)1024 * 2048 * 2;
    float* bias_all = (float*)wsp;     wsp += 3072 * 4;

    cvt_code<<<(M_ * 1024 / 8 + 255) / 256, 256, 0, stream>>>(code, codeh, M_ * 1024 / 8);
    cvt_wqkv<<<(3072 * 128 + 255) / 256, 256, 0, stream>>>(Wq, Wk, Wv, bq, bk, bv, Wt, bias_all);
    cvt_wo<<<(1024 * 256 + 255) / 256, 256, 0, stream>>>(Wo, Wot);

    // QKV projection: [M,1024] x [1024,3072] -> QKV f16 [M][3072]
    gemm_f16_8p<false><<<(M_ / 256) * (3072 / 256), 512, 0, stream>>>(
        codeh, codeh, 1024, Wt, bias_all, (void*)QKV, 3072, 1024, 3072 / 256);

    attn_pdg_mfma<<<dim3(B_, H_), 256, 0, stream>>>(QKV, Rel, resh);

    // Output projection: [M, 2048(=resh|codeh)] x [2048,1024] -> out f32
    gemm_f16_8p<true><<<(M_ / 256) * (1024 / 256), 512, 0, stream>>>(
        resh, codeh, 1024, Wot, bo, (void*)out, 1024, 2048, 1024 / 256);
}